// Round 12
// baseline (38.784 us; speedup 1.0000x reference)
//
#include <hip/hip_runtime.h>

#define BATCH 32
#define NN 116
#define EE 1346
#define HH 64
#define SPLITS 8
#define ECH 170        // K per split: 8*170 = 1360 >= 1346
#define MBLK 256       // 8 splits x 32 batches

typedef __attribute__((ext_vector_type(8))) short bf16x8;
typedef __attribute__((ext_vector_type(4))) float f32x4;

// single-instruction packed f32->bf16 (RNE)
__device__ __forceinline__ unsigned int cvtpk(float a, float b) {
    unsigned int r;
    asm("v_cvt_pk_bf16_f32 %0, %1, %2" : "=v"(r) : "v"(a), "v"(b));
    return r;
}
__device__ __forceinline__ unsigned short bf16_1(float a) {
    union { float f; unsigned int u; } ua; ua.f = a;
    return (unsigned short)((ua.u + 0x7FFFu + ((ua.u >> 16) & 1u)) >> 16);
}
__device__ __forceinline__ float bf2f(unsigned int bits16) {
    union { unsigned int u; float f; } x; x.u = bits16 << 16;
    return x.f;
}

// ===== K1 (256 blocks x 512): per block = (split s, batch b) =====
//  - mult1 partial: single-shot staging (all loads upfront, 2 barriers, 48-MFMA cluster)
//  - 15-row share of HvW[b] (wave = one row, h lanes)
//  - block 0: out seed
__global__ __launch_bounds__(512) void stage1_kernel(
    const float* __restrict__ T, const float* __restrict__ He,
    const float* __restrict__ pv,
    const float* __restrict__ Hv, const float* __restrict__ Wv,
    const float* __restrict__ bfc,
    unsigned short* __restrict__ part16, float* __restrict__ HvW,
    float* __restrict__ out)
{
    const int blk = blockIdx.x;
    const int tid = threadIdx.x;
    const int s = blk & 7, b = blk >> 3;
    const int e0 = s * ECH;
    const int cnt = min(ECH, EE - e0);        // 170 or 156

    __shared__ float del[192];
    __shared__ unsigned int Tt[3 * 128 * 32];    // 3 chunks [128][64k] bf16, swizzled, 48KB
    __shared__ unsigned int dTt[3 * 128 * 32];   // de-scaled copy, 48KB

    if (blk == 0 && tid < BATCH * 4) out[tid] = bfc[tid & 3];

    const int srow = tid >> 2;     // staging row 0..127
    const int q    = tid & 3;      // 16-k quarter of each 64-k chunk
    const bool rowok = srow < NN;
    const float* Trow = T + ((size_t)b * NN + srow) * EE + e0;

    // ---- issue ALL T loads upfront (24 float2/thread, one latency round-trip)
    float2 pf[24];
    #pragma unroll
    for (int c = 0; c < 3; ++c) {
        #pragma unroll
        for (int j = 0; j < 8; ++j) {
            const int k = c * 64 + q * 16 + 2 * j;
            float2 v = {0.f, 0.f};
            if (c < 2) {                       // k <= 126 < 156 <= cnt: no bounds check
                if (rowok) v = *(const float2*)&Trow[k];
            } else {
                if (rowok && k + 1 < cnt) v = *(const float2*)&Trow[k];
                else if (rowok && k < cnt) v.x = Trow[k];
            }
            pf[c * 8 + j] = v;
        }
    }

    // ---- del = He . p_v (loads overlap the T loads in flight)
    {
        const float p0 = pv[0], p1 = pv[1], p2 = pv[2], p3 = pv[3], p4 = pv[4];
        for (int i = tid; i < 192; i += 512) {
            float v = 0.f;
            if (i < cnt) {
                const float* he = He + (size_t)(b * EE + e0 + i) * 5;
                v = he[0]*p0 + he[1]*p1 + he[2]*p2 + he[3]*p3 + he[4]*p4;
            }
            del[i] = v;
        }
    }
    __syncthreads();               // del ready

    // ---- pack all 3 chunks into LDS
    {
        const int swz = (srow & 7) << 4;
        #pragma unroll
        for (int c = 0; c < 3; ++c) {
            const int k0 = c * 64 + q * 16;
            uint4 t0, t1, d0, d1;
            unsigned int* tp0 = &t0.x;  unsigned int* tp1 = &t1.x;
            unsigned int* dp0 = &d0.x;  unsigned int* dp1 = &d1.x;
            #pragma unroll
            for (int j = 0; j < 4; ++j) {
                const float2 va = pf[c * 8 + j];
                const float2 vb = pf[c * 8 + 4 + j];
                const float2 da = *(const float2*)&del[k0 + 2 * j];
                const float2 db = *(const float2*)&del[k0 + 8 + 2 * j];
                tp0[j] = cvtpk(va.x, va.y);
                tp1[j] = cvtpk(vb.x, vb.y);
                dp0[j] = cvtpk(va.x * da.x, va.y * da.y);
                dp1[j] = cvtpk(vb.x * db.x, vb.y * db.y);
            }
            const int bo = c * 16384 + srow * 128 + q * 32;   // chunk base + row + quarter (bytes)
            *(uint4*)((char*)Tt  + (c * 16384 + ((srow * 128 + q * 32)      ^ swz))) = t0;
            *(uint4*)((char*)Tt  + (c * 16384 + ((srow * 128 + q * 32 + 16) ^ swz))) = t1;
            *(uint4*)((char*)dTt + (c * 16384 + ((srow * 128 + q * 32)      ^ swz))) = d0;
            *(uint4*)((char*)dTt + (c * 16384 + ((srow * 128 + q * 32 + 16) ^ swz))) = d1;
            (void)bo;
        }
    }
    __syncthreads();               // tiles ready

    // ---- 48-MFMA cluster (wave tile = 64 rows x 32 cols)
    const int w = tid >> 6, lane = tid & 63;
    const int wr = w >> 2, wc = w & 3;
    const int rl = lane & 15, g = lane >> 4;

    auto fragT = [&](const unsigned int* base, int c, int row, int kkb) -> bf16x8 {
        return *(const bf16x8*)((const char*)base +
               (c * 16384 + ((row * 128 + kkb + g * 16) ^ ((row & 7) << 4))));
    };

    f32x4 acc[4][2] = {};
    #pragma unroll
    for (int c = 0; c < 3; ++c) {
        #pragma unroll
        for (int kk = 0; kk < 2; ++kk) {
            bf16x8 af[4], bf[2];
            #pragma unroll
            for (int i = 0; i < 4; ++i) af[i] = fragT(dTt, c, wr * 64 + i * 16 + rl, kk * 64);
            #pragma unroll
            for (int j = 0; j < 2; ++j) bf[j] = fragT(Tt,  c, wc * 32 + j * 16 + rl, kk * 64);
            #pragma unroll
            for (int tn = 0; tn < 4; ++tn)
                #pragma unroll
                for (int tm = 0; tm < 2; ++tm)
                    acc[tn][tm] = __builtin_amdgcn_mfma_f32_16x16x32_bf16(
                        af[tn], bf[tm], acc[tn][tm], 0, 0, 0);
        }
    }

    // ---- epilogue: bf16 partials, part16[b][n][s][m]
    #pragma unroll
    for (int tn = 0; tn < 4; ++tn) {
        #pragma unroll
        for (int r = 0; r < 4; ++r) {
            const int grow = wr * 64 + tn * 16 + g * 4 + r;
            if (grow >= NN) continue;
            unsigned short* rowp = part16 + (((size_t)b * NN + grow) * SPLITS + s) * 128;
            #pragma unroll
            for (int tm = 0; tm < 2; ++tm)
                rowp[wc * 32 + tm * 16 + rl] = bf16_1(acc[tn][tm][r]);
        }
    }

    // ---- HvW share: rows [s*15, s*15+nrows), wave = one row x 64 h
    {
        const int h = tid & 63;
        const int ridx = tid >> 6;                 // 0..7
        const int rbase = s * 15;
        const int nrows = min(15, NN - rbase);     // 15 (s<7) or 11 (s==7)
        for (int rr = ridx; rr < nrows; rr += 8) {
            const int n = rbase + rr;
            const float* hv = Hv + ((size_t)b * NN + n) * NN;
            float a = 0.f;
            #pragma unroll 4
            for (int k = 0; k < NN; ++k)
                a = fmaf(hv[k], Wv[k * HH + h], a);
            HvW[((size_t)b * NN + n) * HH + h] = a;
        }
    }
}

// ====== K2 (MFMA): per block = (b, 16-row slice). adjA build -> MFMA vs LDS HvWT
//        -> LeakyReLU -> slice-pool -> head partial atomics into bias-seeded out ======
__global__ __launch_bounds__(256) void stage2_kernel(
    const unsigned short* __restrict__ part16, const float* __restrict__ Av,
    const float* __restrict__ HvW, const float* __restrict__ bv,
    const float* __restrict__ Wfc, float* __restrict__ out)
{
    const int blk = blockIdx.x;          // 32 b x 8 slices
    const int b = blk >> 3;
    const int n0 = (blk & 7) * 16;
    const int tid = threadIdx.x;
    const int w = tid >> 6, lane = tid & 63;
    const int rl = lane & 15, g = lane >> 4;

    __shared__ unsigned int Cb[4096];    // HvWT bf16 [h=64][n=128], swizzled, 16KB
    __shared__ unsigned int Ab[1024];    // adjA bf16 [r=16][m=128], swizzled, 4KB
    __shared__ float sl[64];

    // HvWT staging (HvW[b] is L2-resident; 8 blocks share it)
    for (int idx = tid; idx < 64 * 64; idx += 256) {
        const int h = idx & 63, np = idx >> 6;
        const int n = 2 * np;
        const float v0 = (n < NN)     ? HvW[((size_t)b * NN + n) * HH + h]     : 0.f;
        const float v1 = (n + 1 < NN) ? HvW[((size_t)b * NN + n + 1) * HH + h] : 0.f;
        *(unsigned int*)((char*)Cb + ((h * 256 + np * 4) ^ ((h & 7) << 4))) = cvtpk(v0, v1);
    }

    // adjA build: thread -> (r = tid>>4, 8 consecutive m at m0)
    {
        const int r = tid >> 4, m0 = (tid & 15) * 8;
        const int n = n0 + r;
        float ms[8] = {0.f,0.f,0.f,0.f,0.f,0.f,0.f,0.f};
        unsigned int outw[4];
        if (n < NN) {
            const unsigned short* pp = part16 + (((size_t)b * NN + n) * SPLITS) * 128 + m0;
            #pragma unroll
            for (int s = 0; s < SPLITS; ++s) {
                const uint4 u = *(const uint4*)(pp + (size_t)s * 128);
                const unsigned int* up = &u.x;
                #pragma unroll
                for (int j = 0; j < 4; ++j) {
                    ms[2*j]   += bf2f(up[j] & 0xffffu);
                    ms[2*j+1] += bf2f(up[j] >> 16);
                }
            }
            const float* avp = Av + ((size_t)b * NN + n) * NN;
            #pragma unroll
            for (int j = 0; j < 4; ++j) {
                const int m = m0 + 2 * j;
                const float a0 = (m < NN)     ? avp[m]     : 0.f;
                const float a1 = (m + 1 < NN) ? avp[m + 1] : 0.f;
                const float v0 = a0 * ((m     == n) ? 1.0f : ms[2*j]);
                const float v1 = a1 * ((m + 1 == n) ? 1.0f : ms[2*j+1]);
                outw[j] = cvtpk(v0, v1);
            }
        } else {
            outw[0] = outw[1] = outw[2] = outw[3] = 0u;
        }
        *(uint4*)((char*)Ab + ((r * 256 + m0 * 2) ^ ((r & 7) << 4))) = *(uint4*)outw;
    }
    __syncthreads();

    // C2 tile = adjA(16 x 128) @ HvWT^T : wave w -> h-range w*16..+15
    f32x4 acc = {};
    #pragma unroll
    for (int kk = 0; kk < 4; ++kk) {
        const int hrow = w * 16 + rl;
        const bf16x8 a  = *(const bf16x8*)((const char*)Ab +
                          ((rl * 256 + kk * 64 + g * 16) ^ ((rl & 7) << 4)));
        const bf16x8 bb = *(const bf16x8*)((const char*)Cb +
                          ((hrow * 256 + kk * 64 + g * 16) ^ ((hrow & 7) << 4)));
        acc = __builtin_amdgcn_mfma_f32_16x16x32_bf16(a, bb, acc, 0, 0, 0);
    }
    // D[A-row = g*4+r][B-row(h) = w*16+rl]; LeakyReLU + pool over this slice's rows
    {
        const int h = w * 16 + rl;
        const float bias = bv[h];
        float s = 0.f;
        #pragma unroll
        for (int r = 0; r < 4; ++r) {
            const int n = n0 + g * 4 + r;
            if (n < NN) {
                const float x = acc[r] + bias;
                s += (x >= 0.f) ? x : 0.01f * x;   // LeakyReLU(0.01)
            }
        }
        s += __shfl_xor(s, 16);
        s += __shfl_xor(s, 32);
        if (g == 0) sl[h] = s;
    }
    __syncthreads();

    // head partial: out[b,o] += (1/N) * sl . Wfc[:,o]
    if (tid < 4) {
        float a = 0.f;
        #pragma unroll 16
        for (int k = 0; k < HH; ++k)
            a = fmaf(sl[k], Wfc[k * 4 + tid], a);
        atomicAdd(&out[b * 4 + tid], a * (1.0f / NN));
    }
}

extern "C" void kernel_launch(void* const* d_in, const int* in_sizes, int n_in,
                              void* d_out, int out_size, void* d_ws, size_t ws_size,
                              hipStream_t stream) {
    const float* Hv  = (const float*)d_in[0];
    const float* He  = (const float*)d_in[1];
    const float* Av  = (const float*)d_in[2];
    // d_in[3] (adj_e) dead
    const float* T_  = (const float*)d_in[4];
    const float* Wv  = (const float*)d_in[5];
    const float* pv  = (const float*)d_in[6];
    const float* bv  = (const float*)d_in[7];
    // d_in[8,9,10] (W_e, p_e, b_e) dead
    const float* Wfc = (const float*)d_in[11];
    const float* bfc = (const float*)d_in[12];
    float* out = (float*)d_out;

    unsigned short* part16 = (unsigned short*)d_ws;                     // [32][116][8][128] bf16
    float* HvW = (float*)(part16 + (size_t)BATCH * NN * SPLITS * 128);  // [32][116][64] f32

    stage1_kernel<<<MBLK, 512, 0, stream>>>(
        T_, He, pv, Hv, Wv, bfc, part16, HvW, out);
    stage2_kernel<<<BATCH * 8, 256, 0, stream>>>(
        part16, Av, HvW, bv, Wfc, out);
}

// Round 15
// 31.778 us; speedup vs baseline: 1.2205x; 1.2205x over previous
//
#include <hip/hip_runtime.h>

#define BATCH 32
#define NN 116
#define EE 1346
#define HH 64
#define SPLITS 8
#define ECH 170        // K per split: 8*170 = 1360 >= 1346
#define MBLK 256       // mult1 blocks: 8 splits x 32 batches
#define HVBLK 116      // hvw blocks: 3712 rows / 32 per block
#define GRID1 (MBLK + HVBLK + 1)

typedef __attribute__((ext_vector_type(8))) short bf16x8;
typedef __attribute__((ext_vector_type(4))) float f32x4;

// single-instruction packed f32->bf16 (RNE)
__device__ __forceinline__ unsigned int cvtpk(float a, float b) {
    unsigned int r;
    asm("v_cvt_pk_bf16_f32 %0, %1, %2" : "=v"(r) : "v"(a), "v"(b));
    return r;
}
__device__ __forceinline__ unsigned short bf16_1(float a) {
    union { float f; unsigned int u; } ua; ua.f = a;
    return (unsigned short)((ua.u + 0x7FFFu + ((ua.u >> 16) & 1u)) >> 16);
}
__device__ __forceinline__ float bf2f(unsigned int bits16) {
    union { unsigned int u; float f; } x; x.u = bits16 << 16;
    return x.f;
}

// ===== K1: mult1 partials (MFMA, 512thr, K=64, 3 steps, bf16 out) + HvW GEMV + out init =====
__global__ __launch_bounds__(512) void stage1_kernel(
    const float* __restrict__ T, const float* __restrict__ He,
    const float* __restrict__ pv,
    const float* __restrict__ Hv, const float* __restrict__ Wv,
    const float* __restrict__ bfc,
    unsigned short* __restrict__ part16, float* __restrict__ HvW,
    float* __restrict__ out)
{
    const int blk = blockIdx.x;
    const int tid = threadIdx.x;

    __shared__ float del[192];
    __shared__ unsigned int Tt[128 * 32];    // [row=128][64k] bf16, XOR-swizzled, 16KB
    __shared__ unsigned int dTt[128 * 32];   // de-scaled copy, 16KB

    if (blk < MBLK) {
        // ---- mult1: part[b][n][s][m] = sum_{e in split s} T[n,e]*de[e]*T[m,e]
        const int s = blk & 7, b = blk >> 3;
        const int e0 = s * ECH;
        const int cnt = min(ECH, EE - e0);        // 170 or 156
        const int nsteps = 3;

        {
            const float p0 = pv[0], p1 = pv[1], p2 = pv[2], p3 = pv[3], p4 = pv[4];
            for (int i = tid; i < 192; i += 512) {
                float v = 0.f;
                if (i < cnt) {
                    const float* he = He + (size_t)(b * EE + e0 + i) * 5;
                    v = he[0]*p0 + he[1]*p1 + he[2]*p2 + he[3]*p3 + he[4]*p4;
                }
                del[i] = v;
            }
        }

        const int srow = tid >> 2;     // staging row 0..127
        const int q    = tid & 3;      // 16-k quarter of the 64-k chunk
        const bool rowok = srow < NN;
        const float* Trow = T + ((size_t)b * NN + srow) * EE + e0;

        float2 pf[8];
        // steps 0,1 (k max = 127 < 156 <= cnt): no per-element compares
        auto pref_fast = [&](int c) {
            const int k0 = c * 64 + q * 16;
            #pragma unroll
            for (int j = 0; j < 8; ++j) {
                float2 v = {0.f, 0.f};
                if (rowok) v = *(const float2*)&Trow[k0 + 2 * j];
                pf[j] = v;
            }
        };
        auto pref_chk = [&](int c) {
            const int k0 = c * 64 + q * 16;
            #pragma unroll
            for (int j = 0; j < 8; ++j) {
                float2 v = {0.f, 0.f};
                const int k = k0 + 2 * j;
                if (rowok && k + 1 < cnt) v = *(const float2*)&Trow[k];
                else if (rowok && k < cnt) v.x = Trow[k];
                pf[j] = v;
            }
        };
        auto wlds = [&](int c) {
            const int k0 = c * 64 + q * 16;
            uint4 t0, t1, d0, d1;
            unsigned int* tp0 = &t0.x;  unsigned int* tp1 = &t1.x;
            unsigned int* dp0 = &d0.x;  unsigned int* dp1 = &d1.x;
            #pragma unroll
            for (int j = 0; j < 4; ++j) {
                const float2 va = pf[j];
                const float2 vb = pf[4 + j];
                const float2 da = *(const float2*)&del[k0 + 2 * j];
                const float2 db = *(const float2*)&del[k0 + 8 + 2 * j];
                tp0[j] = cvtpk(va.x, va.y);
                tp1[j] = cvtpk(vb.x, vb.y);
                dp0[j] = cvtpk(va.x * da.x, va.y * da.y);
                dp1[j] = cvtpk(vb.x * db.x, vb.y * db.y);
            }
            const int swz = (srow & 7) << 4;
            *(uint4*)((char*)Tt  + (((srow * 128 + q * 32))      ^ swz)) = t0;
            *(uint4*)((char*)Tt  + (((srow * 128 + q * 32 + 16)) ^ swz)) = t1;
            *(uint4*)((char*)dTt + (((srow * 128 + q * 32))      ^ swz)) = d0;
            *(uint4*)((char*)dTt + (((srow * 128 + q * 32 + 16)) ^ swz)) = d1;
        };

        const int w = tid >> 6, lane = tid & 63;
        const int wr = w >> 2, wc = w & 3;
        const int rl = lane & 15, g = lane >> 4;

        auto fragT = [&](const unsigned int* base, int row, int kkb) -> bf16x8 {
            return *(const bf16x8*)((const char*)base + ((row * 128 + kkb + g * 16) ^ ((row & 7) << 4)));
        };

        f32x4 acc[4][2] = {};

        pref_fast(0);
        __syncthreads();               // del ready

        for (int c = 0; c < nsteps; ++c) {
            wlds(c);
            // issue next chunk's loads BEFORE the barrier: in flight across it
            if (c + 1 == nsteps - 1) pref_fast(c + 1);
            else if (c + 1 < nsteps)  pref_chk(c + 1);
            __syncthreads();           // tile visible
            #pragma unroll
            for (int kk = 0; kk < 2; ++kk) {
                bf16x8 af[4], bf[2];
                #pragma unroll
                for (int i = 0; i < 4; ++i) af[i] = fragT(dTt, wr * 64 + i * 16 + rl, kk * 64);
                #pragma unroll
                for (int j = 0; j < 2; ++j) bf[j] = fragT(Tt,  wc * 32 + j * 16 + rl, kk * 64);
                #pragma unroll
                for (int tn = 0; tn < 4; ++tn)
                    #pragma unroll
                    for (int tm = 0; tm < 2; ++tm)
                        acc[tn][tm] = __builtin_amdgcn_mfma_f32_16x16x32_bf16(
                            af[tn], bf[tm], acc[tn][tm], 0, 0, 0);
            }
            __syncthreads();
        }

        // epilogue: bf16 partials, part16[b][n][s][m]
        #pragma unroll
        for (int tn = 0; tn < 4; ++tn) {
            #pragma unroll
            for (int r = 0; r < 4; ++r) {
                const int grow = wr * 64 + tn * 16 + g * 4 + r;
                if (grow >= NN) continue;
                unsigned short* rowp = part16 + (((size_t)b * NN + grow) * SPLITS + s) * 128;
                #pragma unroll
                for (int tm = 0; tm < 2; ++tm)
                    rowp[wc * 32 + tm * 16 + rl] = bf16_1(acc[tn][tm][r]);
            }
        }
    } else if (blk < MBLK + HVBLK) {
        // ---- HvW: 32 rows per block, 4 rows per wave (4-way ILP)
        const int l0 = (blk - MBLK) * 32 + (tid >> 6) * 4;
        const int h  = tid & 63;
        const float* hv0 = Hv + (size_t)(l0 + 0) * NN;
        const float* hv1 = Hv + (size_t)(l0 + 1) * NN;
        const float* hv2 = Hv + (size_t)(l0 + 2) * NN;
        const float* hv3 = Hv + (size_t)(l0 + 3) * NN;
        float a0 = 0.f, a1 = 0.f, a2 = 0.f, a3 = 0.f;
        #pragma unroll 4
        for (int k = 0; k < NN; ++k) {
            const float wv = Wv[k * HH + h];
            a0 = fmaf(hv0[k], wv, a0);
            a1 = fmaf(hv1[k], wv, a1);
            a2 = fmaf(hv2[k], wv, a2);
            a3 = fmaf(hv3[k], wv, a3);
        }
        HvW[(size_t)(l0 + 0) * HH + h] = a0;
        HvW[(size_t)(l0 + 1) * HH + h] = a1;
        HvW[(size_t)(l0 + 2) * HH + h] = a2;
        HvW[(size_t)(l0 + 3) * HH + h] = a3;
    } else {
        // ---- out init: out[b,o] = b_fc[o]
        if (tid < BATCH * 4) out[tid] = bfc[tid & 3];
    }
}

// ====== K2 (MFMA): per block = (b, 16-row slice). adjA build -> MFMA vs LDS HvWT
//        -> LeakyReLU -> slice-pool -> head partial atomics into bias-seeded out ======
__global__ __launch_bounds__(256) void stage2_kernel(
    const unsigned short* __restrict__ part16, const float* __restrict__ Av,
    const float* __restrict__ HvW, const float* __restrict__ bv,
    const float* __restrict__ Wfc, float* __restrict__ out)
{
    const int blk = blockIdx.x;          // 32 b x 8 slices
    const int b = blk >> 3;
    const int n0 = (blk & 7) * 16;
    const int tid = threadIdx.x;
    const int w = tid >> 6, lane = tid & 63;
    const int rl = lane & 15, g = lane >> 4;

    __shared__ unsigned int Cb[4096];    // HvWT bf16 [h=64][n=128], swizzled, 16KB
    __shared__ unsigned int Ab[1024];    // adjA bf16 [r=16][m=128], swizzled, 4KB
    __shared__ float sl[64];

    // HvWT staging (HvW[b] is L2-resident; 8 blocks share it)
    for (int idx = tid; idx < 64 * 64; idx += 256) {
        const int h = idx & 63, np = idx >> 6;
        const int n = 2 * np;
        const float v0 = (n < NN)     ? HvW[((size_t)b * NN + n) * HH + h]     : 0.f;
        const float v1 = (n + 1 < NN) ? HvW[((size_t)b * NN + n + 1) * HH + h] : 0.f;
        *(unsigned int*)((char*)Cb + ((h * 256 + np * 4) ^ ((h & 7) << 4))) = cvtpk(v0, v1);
    }

    // adjA build: thread -> (r = tid>>4, 8 consecutive m at m0)
    {
        const int r = tid >> 4, m0 = (tid & 15) * 8;
        const int n = n0 + r;
        float ms[8] = {0.f,0.f,0.f,0.f,0.f,0.f,0.f,0.f};
        unsigned int outw[4];
        if (n < NN) {
            const unsigned short* pp = part16 + (((size_t)b * NN + n) * SPLITS) * 128 + m0;
            #pragma unroll
            for (int s = 0; s < SPLITS; ++s) {
                const uint4 u = *(const uint4*)(pp + (size_t)s * 128);
                const unsigned int* up = &u.x;
                #pragma unroll
                for (int j = 0; j < 4; ++j) {
                    ms[2*j]   += bf2f(up[j] & 0xffffu);
                    ms[2*j+1] += bf2f(up[j] >> 16);
                }
            }
            const float* avp = Av + ((size_t)b * NN + n) * NN;
            #pragma unroll
            for (int j = 0; j < 4; ++j) {
                const int m = m0 + 2 * j;
                const float a0 = (m < NN)     ? avp[m]     : 0.f;
                const float a1 = (m + 1 < NN) ? avp[m + 1] : 0.f;
                const float v0 = a0 * ((m     == n) ? 1.0f : ms[2*j]);
                const float v1 = a1 * ((m + 1 == n) ? 1.0f : ms[2*j+1]);
                outw[j] = cvtpk(v0, v1);
            }
        } else {
            outw[0] = outw[1] = outw[2] = outw[3] = 0u;
        }
        *(uint4*)((char*)Ab + ((r * 256 + m0 * 2) ^ ((r & 7) << 4))) = *(uint4*)outw;
    }
    __syncthreads();

    // C2 tile = adjA(16 x 128) @ HvWT^T : wave w -> h-range w*16..+15
    f32x4 acc = {};
    #pragma unroll
    for (int kk = 0; kk < 4; ++kk) {
        const int hrow = w * 16 + rl;
        const bf16x8 a  = *(const bf16x8*)((const char*)Ab +
                          ((rl * 256 + kk * 64 + g * 16) ^ ((rl & 7) << 4)));
        const bf16x8 bb = *(const bf16x8*)((const char*)Cb +
                          ((hrow * 256 + kk * 64 + g * 16) ^ ((hrow & 7) << 4)));
        acc = __builtin_amdgcn_mfma_f32_16x16x32_bf16(a, bb, acc, 0, 0, 0);
    }
    // D[A-row = g*4+r][B-row(h) = w*16+rl]; LeakyReLU + pool over this slice's rows
    {
        const int h = w * 16 + rl;
        const float bias = bv[h];
        float s = 0.f;
        #pragma unroll
        for (int r = 0; r < 4; ++r) {
            const int n = n0 + g * 4 + r;
            if (n < NN) {
                const float x = acc[r] + bias;
                s += (x >= 0.f) ? x : 0.01f * x;   // LeakyReLU(0.01)
            }
        }
        s += __shfl_xor(s, 16);
        s += __shfl_xor(s, 32);
        if (g == 0) sl[h] = s;
    }
    __syncthreads();

    // head partial: out[b,o] += (1/N) * sl . Wfc[:,o]
    if (tid < 4) {
        float a = 0.f;
        #pragma unroll 16
        for (int k = 0; k < HH; ++k)
            a = fmaf(sl[k], Wfc[k * 4 + tid], a);
        atomicAdd(&out[b * 4 + tid], a * (1.0f / NN));
    }
}

extern "C" void kernel_launch(void* const* d_in, const int* in_sizes, int n_in,
                              void* d_out, int out_size, void* d_ws, size_t ws_size,
                              hipStream_t stream) {
    const float* Hv  = (const float*)d_in[0];
    const float* He  = (const float*)d_in[1];
    const float* Av  = (const float*)d_in[2];
    // d_in[3] (adj_e) dead
    const float* T_  = (const float*)d_in[4];
    const float* Wv  = (const float*)d_in[5];
    const float* pv  = (const float*)d_in[6];
    const float* bv  = (const float*)d_in[7];
    // d_in[8,9,10] (W_e, p_e, b_e) dead
    const float* Wfc = (const float*)d_in[11];
    const float* bfc = (const float*)d_in[12];
    float* out = (float*)d_out;

    unsigned short* part16 = (unsigned short*)d_ws;                     // [32][116][8][128] bf16
    float* HvW = (float*)(part16 + (size_t)BATCH * NN * SPLITS * 128);  // [32][116][64] f32

    stage1_kernel<<<GRID1, 512, 0, stream>>>(
        T_, He, pv, Hv, Wv, bfc, part16, HvW, out);
    stage2_kernel<<<BATCH * 8, 256, 0, stream>>>(
        part16, Av, HvW, bv, Wfc, out);
}